// Round 1
// baseline (473.790 us; speedup 1.0000x reference)
//
#include <hip/hip_runtime.h>
#include <hip/hip_bf16.h>

// Causal attention block: out = softmax(mask(QK^T/sqrt(D))) V projections.
// B=2, T=2048, C=2048, H=16, D=128. fp32 I/O, bf16 MFMA compute internally.
//
// Pipeline:
//   1. cvt: x, wq, wk, wv, wo  fp32 -> bf16
//   2. gemm_bt<0>: Q = x@wq.T  -> [B,H,T,D] bf16
//      gemm_bt<0>: K = x@wk.T  -> [B,H,T,D] bf16
//      gemm_bt<1>: V = x@wv.T  -> [B,H,D,T] bf16 (transposed for PV frags)
//   3. attn_fwd: flash attention w/ online softmax -> [B,T,H*D] bf16
//   4. gemm_bt<2>: out = attn@wo.T -> fp32 d_out

#define BB 2
#define TT 2048
#define CC 2048
#define HH 16
#define DD 128
#define MM (BB*TT)   // 4096

typedef __bf16 bf16x8 __attribute__((ext_vector_type(8)));
typedef __bf16 bf16x4 __attribute__((ext_vector_type(4)));
typedef float  f32x4  __attribute__((ext_vector_type(4)));

#define MFMA16(a, b, c) __builtin_amdgcn_mfma_f32_16x16x32_bf16((a), (b), (c), 0, 0, 0)

__device__ __forceinline__ void g2lds16(const void* g, void* l) {
    __builtin_amdgcn_global_load_lds(
        (const __attribute__((address_space(1))) void*)g,
        (__attribute__((address_space(3))) void*)l,
        16, 0, 0);
}

// ---------------------------------------------------------------- convert
__global__ __launch_bounds__(256) void cvt_f32_bf16(
    const float* __restrict__ in, __bf16* __restrict__ out, int n4)
{
    const int i = blockIdx.x * 256 + threadIdx.x;
    if (i < n4) {
        const float4 v = ((const float4*)in)[i];
        bf16x4 o;
        o.x = (__bf16)v.x; o.y = (__bf16)v.y;
        o.z = (__bf16)v.z; o.w = (__bf16)v.w;
        ((bf16x4*)out)[i] = o;
    }
}

// ---------------------------------------------------------------- GEMM (B^T)
// C[m][n] = sum_k A[m][k] * Wt[n][k].  M=4096, N=2048, K=2048.
// 128x128 tile, BK=32, 4 waves in 2x2, each wave 64x64 (4x4 16x16 frags).
// MODE 0: write bf16 [B,H,T,D]   (m->(b,t), n->(h,d))
// MODE 1: write bf16 [B,H,D,T]   (V transposed)
// MODE 2: write fp32 row-major [M][N]
template<int MODE>
__global__ __launch_bounds__(256, 2) void gemm_bt(
    const __bf16* __restrict__ A, const __bf16* __restrict__ Wt,
    void* __restrict__ out)
{
    __shared__ __align__(16) __bf16 As[128*32];
    __shared__ __align__(16) __bf16 Bs[128*32];

    const int n0  = blockIdx.x * 128;
    const int m0  = blockIdx.y * 128;
    const int tid = threadIdx.x;
    const int w   = tid >> 6, lane = tid & 63;
    const int wr  = w >> 1,  wc  = w & 1;
    const int lo  = lane & 15, hi = lane >> 4;
    const int rs  = lane >> 2;            // staging row within 16-row chunk
    const int cs  = (lane & 3) << 3;      // staging col elem (0,8,16,24)

    f32x4 acc[4][4] = {};

    for (int kt = 0; kt < CC/32; ++kt) {
        const int k0 = kt << 5;
        __syncthreads();
        #pragma unroll
        for (int i = 0; i < 2; ++i) {
            const int c = 2*w + i;        // 8 chunks of 1KB each for A and B
            g2lds16(A  + (size_t)(m0 + c*16 + rs)*CC + k0 + cs, As + c*512);
            g2lds16(Wt + (size_t)(n0 + c*16 + rs)*CC + k0 + cs, Bs + c*512);
        }
        __syncthreads();

        bf16x8 af[4], bfr[4];
        #pragma unroll
        for (int i = 0; i < 4; ++i) {
            af[i]  = *(const bf16x8*)(As + (wr*64 + i*16 + lo)*32 + hi*8);
            bfr[i] = *(const bf16x8*)(Bs + (wc*64 + i*16 + lo)*32 + hi*8);
        }
        #pragma unroll
        for (int i = 0; i < 4; ++i)
            #pragma unroll
            for (int j = 0; j < 4; ++j)
                acc[i][j] = MFMA16(af[i], bfr[j], acc[i][j]);
    }

    // epilogue: C/D layout col=lane&15, row=(lane>>4)*4+r  [m89-verified]
    #pragma unroll
    for (int i = 0; i < 4; ++i) {
        #pragma unroll
        for (int j = 0; j < 4; ++j) {
            #pragma unroll
            for (int r = 0; r < 4; ++r) {
                const int row = m0 + wr*64 + i*16 + hi*4 + r;   // m
                const int col = n0 + wc*64 + j*16 + lo;         // n
                const float v = acc[i][j][r];
                if (MODE == 0) {
                    const int b = row >> 11, t = row & (TT-1);
                    const int h = col >> 7,  d = col & (DD-1);
                    ((__bf16*)out)[(size_t)((b*HH + h)*TT + t)*DD + d] = (__bf16)v;
                } else if (MODE == 1) {
                    const int b = row >> 11, t = row & (TT-1);
                    const int h = col >> 7,  d = col & (DD-1);
                    ((__bf16*)out)[(size_t)((b*HH + h)*DD + d)*TT + t] = (__bf16)v;
                } else {
                    ((float*)out)[(size_t)row*CC + col] = v;
                }
            }
        }
    }
}

// ---------------------------------------------------------------- attention
// Grid (T/64, B*H). 4 waves/block, each wave owns 16 Q rows.
// K tile [64][128] and Vt tile [128][64] staged in LDS per KV step.
// Online softmax; P goes through per-wave LDS to reach MFMA A-layout.
__global__ __launch_bounds__(256, 2) void attn_fwd(
    const __bf16* __restrict__ Q, const __bf16* __restrict__ K,
    const __bf16* __restrict__ Vt, __bf16* __restrict__ O)
{
    __shared__ __align__(16) __bf16 Ks[64*128];   // [kv][d]
    __shared__ __align__(16) __bf16 Vs[128*64];   // [d][kv]
    __shared__ __align__(16) __bf16 Ps[4][16*64]; // per-wave [q][kv]

    const int bh  = blockIdx.y;            // b*H + h
    const int q0  = blockIdx.x * 64;
    const int tid = threadIdx.x;
    const int w   = tid >> 6, lane = tid & 63;
    const int lo  = lane & 15, hi = lane >> 4;

    // Q fragments in registers: rows w*16 + lo, all of D
    const __bf16* Qbase = Q + ((size_t)bh*TT + q0 + w*16 + lo) * DD;
    bf16x8 qf[4];
    #pragma unroll
    for (int kc = 0; kc < 4; ++kc)
        qf[kc] = *(const bf16x8*)(Qbase + kc*32 + hi*8);

    float mrow[4], lrow[4];
    #pragma unroll
    for (int r = 0; r < 4; ++r) { mrow[r] = -1e30f; lrow[r] = 0.f; }
    f32x4 oacc[8] = {};   // out rows q=4*hi+r, cols d = dc*16+lo

    const int qg_base = q0 + w*16 + hi*4;  // + r
    const int ntiles  = q0/64 + 1;         // causal: kv tiles 0..q0/64

    for (int t = 0; t < ntiles; ++t) {
        const int kv0 = t*64;
        __syncthreads();
        #pragma unroll
        for (int i = 0; i < 4; ++i) {
            const int c = 4*w + i;   // 16 chunks of 1KB each for K and Vt
            // K chunk: 4 rows x 128 elems; lane -> row c*4+hi, elem lo*8
            g2lds16(K  + ((size_t)bh*TT + kv0 + c*4 + hi)*DD + lo*8,
                    Ks + c*512);
            // Vt chunk: 8 rows x 64 elems; lane -> row c*8+(lane>>3), elem (lane&7)*8
            g2lds16(Vt + ((size_t)bh*DD + c*8 + (lane>>3))*TT + kv0 + (lane&7)*8,
                    Vs + c*512);
        }
        __syncthreads();

        // S = Q K^T : lane holds S[q=4hi+r][kv=st*16+lo]
        f32x4 s[4];
        #pragma unroll
        for (int st = 0; st < 4; ++st) {
            f32x4 a = {};
            #pragma unroll
            for (int kc = 0; kc < 4; ++kc) {
                const bf16x8 kf = *(const bf16x8*)(Ks + (st*16 + lo)*DD + kc*32 + hi*8);
                a = MFMA16(qf[kc], kf, a);
            }
            s[st] = a;
        }

        // scale + causal mask + row max (reduce over st in-lane, lo cross-lane)
        float pmax[4];
        #pragma unroll
        for (int r = 0; r < 4; ++r) {
            const int qg = qg_base + r;
            float mx = -1e30f;
            #pragma unroll
            for (int st = 0; st < 4; ++st) {
                float v = s[st][r] * 0.08838834764831845f;
                const int kvg = kv0 + st*16 + lo;
                v = (kvg > qg) ? -1e30f : v;
                s[st][r] = v;
                mx = fmaxf(mx, v);
            }
            #pragma unroll
            for (int msk = 1; msk < 16; msk <<= 1)
                mx = fmaxf(mx, __shfl_xor(mx, msk, 64));
            pmax[r] = mx;
        }

        float rsc[4], psum[4];
        #pragma unroll
        for (int r = 0; r < 4; ++r) {
            const float mnew = fmaxf(mrow[r], pmax[r]);
            rsc[r]  = __expf(mrow[r] - mnew);
            mrow[r] = mnew;
            float ps = 0.f;
            #pragma unroll
            for (int st = 0; st < 4; ++st) {
                const float pv = __expf(s[st][r] - mnew);
                s[st][r] = pv;
                ps += pv;
            }
            psum[r] = ps;
        }
        #pragma unroll
        for (int r = 0; r < 4; ++r) {
            #pragma unroll
            for (int msk = 1; msk < 16; msk <<= 1)
                psum[r] += __shfl_xor(psum[r], msk, 64);
            lrow[r] = lrow[r]*rsc[r] + psum[r];
        }
        #pragma unroll
        for (int dc = 0; dc < 8; ++dc)
            #pragma unroll
            for (int r = 0; r < 4; ++r)
                oacc[dc][r] *= rsc[r];

        // P -> per-wave LDS (C-layout out, A-layout back in)
        __bf16* Pw = &Ps[w][0];
        #pragma unroll
        for (int st = 0; st < 4; ++st)
            #pragma unroll
            for (int r = 0; r < 4; ++r)
                Pw[(hi*4 + r)*64 + st*16 + lo] = (__bf16)s[st][r];
        __syncthreads();

        // PV: out[q][d] += P[q][kv] V[kv][d]
        #pragma unroll
        for (int kc2 = 0; kc2 < 2; ++kc2) {
            const bf16x8 pf = *(const bf16x8*)(Pw + lo*64 + kc2*32 + hi*8);
            #pragma unroll
            for (int dc = 0; dc < 8; ++dc) {
                const bf16x8 vf = *(const bf16x8*)(Vs + (dc*16 + lo)*64 + kc2*32 + hi*8);
                oacc[dc] = MFMA16(pf, vf, oacc[dc]);
            }
        }
    }

    // epilogue: normalize and write [B,T,H*D] bf16
    const int b = bh >> 4, h = bh & 15;
    #pragma unroll
    for (int r = 0; r < 4; ++r) {
        const float inv = 1.f / lrow[r];
        const int qg = qg_base + r;
        #pragma unroll
        for (int dc = 0; dc < 8; ++dc) {
            const int d = dc*16 + lo;
            O[(size_t)(b*TT + qg)*CC + h*DD + d] = (__bf16)(oacc[dc][r] * inv);
        }
    }
}

// ---------------------------------------------------------------- launch
extern "C" void kernel_launch(void* const* d_in, const int* in_sizes, int n_in,
                              void* d_out, int out_size, void* d_ws, size_t ws_size,
                              hipStream_t stream) {
    const float* x  = (const float*)d_in[0];
    // d_in[1] = mask (causal, implemented analytically)
    const float* wq = (const float*)d_in[2];
    const float* wk = (const float*)d_in[3];
    const float* wv = (const float*)d_in[4];
    const float* wo = (const float*)d_in[5];

    char* p = (char*)d_ws;
    __bf16* xb  = (__bf16*)p; p += (size_t)MM*CC*2;   // also reused as attn-out
    __bf16* wqb = (__bf16*)p; p += (size_t)CC*CC*2;
    __bf16* wkb = (__bf16*)p; p += (size_t)CC*CC*2;
    __bf16* wvb = (__bf16*)p; p += (size_t)CC*CC*2;
    __bf16* wob = (__bf16*)p; p += (size_t)CC*CC*2;
    __bf16* Qb  = (__bf16*)p; p += (size_t)MM*CC*2;
    __bf16* Kb  = (__bf16*)p; p += (size_t)MM*CC*2;
    __bf16* Vtb = (__bf16*)p; p += (size_t)MM*CC*2;
    __bf16* AOb = xb;  // x no longer needed after QKV GEMMs (stream-ordered)

    cvt_f32_bf16<<<MM*CC/4/256, 256, 0, stream>>>(x,  xb,  MM*CC/4);
    cvt_f32_bf16<<<CC*CC/4/256, 256, 0, stream>>>(wq, wqb, CC*CC/4);
    cvt_f32_bf16<<<CC*CC/4/256, 256, 0, stream>>>(wk, wkb, CC*CC/4);
    cvt_f32_bf16<<<CC*CC/4/256, 256, 0, stream>>>(wv, wvb, CC*CC/4);
    cvt_f32_bf16<<<CC*CC/4/256, 256, 0, stream>>>(wo, wob, CC*CC/4);

    const dim3 gg(CC/128, MM/128);   // (16, 32)
    gemm_bt<0><<<gg, 256, 0, stream>>>(xb, wqb, Qb);
    gemm_bt<0><<<gg, 256, 0, stream>>>(xb, wkb, Kb);
    gemm_bt<1><<<gg, 256, 0, stream>>>(xb, wvb, Vtb);

    attn_fwd<<<dim3(TT/64, BB*HH), 256, 0, stream>>>(Qb, Kb, Vtb, AOb);

    gemm_bt<2><<<gg, 256, 0, stream>>>(AOb, wob, (void*)d_out);
}

// Round 2
// 363.939 us; speedup vs baseline: 1.3018x; 1.3018x over previous
//
#include <hip/hip_runtime.h>
#include <hip/hip_bf16.h>

// Causal attention block: out = softmax(mask(QK^T/sqrt(D))) V projections.
// B=2, T=2048, C=2048, H=16, D=128. fp32 I/O, bf16 MFMA compute internally.
//
// Pipeline:
//   1. cvt: x, wq, wk, wv, wo  fp32 -> bf16
//   2. gemm_bt<0>: Q = x@wq.T  -> [B,H,T,D] bf16
//      gemm_bt<0>: K = x@wk.T  -> [B,H,T,D] bf16
//      gemm_bt<1>: V = x@wv.T  -> [B,H,D,T] bf16 (transposed for PV frags)
//   3. attn_fwd: flash attention, XOR-swizzled LDS, 2-phase double buffer
//   4. gemm_bt<2>: out = attn@wo.T -> fp32 d_out

#define BB 2
#define TT 2048
#define CC 2048
#define HH 16
#define DD 128
#define MM (BB*TT)   // 4096

typedef __bf16 bf16x8 __attribute__((ext_vector_type(8)));
typedef __bf16 bf16x4 __attribute__((ext_vector_type(4)));
typedef float  f32x4  __attribute__((ext_vector_type(4)));

#define MFMA16(a, b, c) __builtin_amdgcn_mfma_f32_16x16x32_bf16((a), (b), (c), 0, 0, 0)

__device__ __forceinline__ void g2lds16(const void* g, void* l) {
    __builtin_amdgcn_global_load_lds(
        (const __attribute__((address_space(1))) void*)g,
        (__attribute__((address_space(3))) void*)l,
        16, 0, 0);
}

// ---------------------------------------------------------------- convert
__global__ __launch_bounds__(256) void cvt_f32_bf16(
    const float* __restrict__ in, __bf16* __restrict__ out, int n4)
{
    const int i = blockIdx.x * 256 + threadIdx.x;
    if (i < n4) {
        const float4 v = ((const float4*)in)[i];
        bf16x4 o;
        o.x = (__bf16)v.x; o.y = (__bf16)v.y;
        o.z = (__bf16)v.z; o.w = (__bf16)v.w;
        ((bf16x4*)out)[i] = o;
    }
}

// ---------------------------------------------------------------- GEMM (B^T)
// C[m][n] = sum_k A[m][k] * Wt[n][k].  M=4096, N=2048, K=2048.
// 128x128 tile, BK=32, 4 waves in 2x2, each wave 64x64 (4x4 16x16 frags).
template<int MODE>
__global__ __launch_bounds__(256, 2) void gemm_bt(
    const __bf16* __restrict__ A, const __bf16* __restrict__ Wt,
    void* __restrict__ out)
{
    __shared__ __align__(16) __bf16 As[128*32];
    __shared__ __align__(16) __bf16 Bs[128*32];

    const int n0  = blockIdx.x * 128;
    const int m0  = blockIdx.y * 128;
    const int tid = threadIdx.x;
    const int w   = tid >> 6, lane = tid & 63;
    const int wr  = w >> 1,  wc  = w & 1;
    const int lo  = lane & 15, hi = lane >> 4;
    const int rs  = lane >> 2;            // staging row within 16-row chunk
    const int cs  = (lane & 3) << 3;      // staging col elem (0,8,16,24)

    f32x4 acc[4][4] = {};

    for (int kt = 0; kt < CC/32; ++kt) {
        const int k0 = kt << 5;
        __syncthreads();
        #pragma unroll
        for (int i = 0; i < 2; ++i) {
            const int c = 2*w + i;        // 8 chunks of 1KB each for A and B
            g2lds16(A  + (size_t)(m0 + c*16 + rs)*CC + k0 + cs, As + c*512);
            g2lds16(Wt + (size_t)(n0 + c*16 + rs)*CC + k0 + cs, Bs + c*512);
        }
        __syncthreads();

        bf16x8 af[4], bfr[4];
        #pragma unroll
        for (int i = 0; i < 4; ++i) {
            af[i]  = *(const bf16x8*)(As + (wr*64 + i*16 + lo)*32 + hi*8);
            bfr[i] = *(const bf16x8*)(Bs + (wc*64 + i*16 + lo)*32 + hi*8);
        }
        #pragma unroll
        for (int i = 0; i < 4; ++i)
            #pragma unroll
            for (int j = 0; j < 4; ++j)
                acc[i][j] = MFMA16(af[i], bfr[j], acc[i][j]);
    }

    // epilogue: C/D layout col=lane&15, row=(lane>>4)*4+r  [m89-verified]
    #pragma unroll
    for (int i = 0; i < 4; ++i) {
        #pragma unroll
        for (int j = 0; j < 4; ++j) {
            #pragma unroll
            for (int r = 0; r < 4; ++r) {
                const int row = m0 + wr*64 + i*16 + hi*4 + r;   // m
                const int col = n0 + wc*64 + j*16 + lo;         // n
                const float v = acc[i][j][r];
                if (MODE == 0) {
                    const int b = row >> 11, t = row & (TT-1);
                    const int h = col >> 7,  d = col & (DD-1);
                    ((__bf16*)out)[(size_t)((b*HH + h)*TT + t)*DD + d] = (__bf16)v;
                } else if (MODE == 1) {
                    const int b = row >> 11, t = row & (TT-1);
                    const int h = col >> 7,  d = col & (DD-1);
                    ((__bf16*)out)[(size_t)((b*HH + h)*DD + d)*TT + t] = (__bf16)v;
                } else {
                    ((float*)out)[(size_t)row*CC + col] = v;
                }
            }
        }
    }
}

// ---------------------------------------------------------------- attention
// Grid (T/64, B*H). 4 waves/block, each wave owns 16 Q rows.
// K tile [64][128] (swz: byte ^= (row&7)<<4, row=byte>>8) and
// Vt tile [128][64] (swz: byte ^= (row&7)<<4, row=byte>>7) double-buffered.
// 2-phase: stage t+1 before compute t; ONE barrier per tile.
// P via per-wave swizzled LDS (no barrier needed).
__global__ __launch_bounds__(256, 2) void attn_fwd(
    const __bf16* __restrict__ Q, const __bf16* __restrict__ K,
    const __bf16* __restrict__ Vt, __bf16* __restrict__ O)
{
    __shared__ __align__(16) __bf16 Ks[2][64*128];   // 32 KB
    __shared__ __align__(16) __bf16 Vs[2][128*64];   // 32 KB
    __shared__ __align__(16) __bf16 Ps[4][16*64];    //  8 KB

    const int bh  = blockIdx.y;            // b*H + h
    const int q0  = blockIdx.x * 64;
    const int tid = threadIdx.x;
    const int w   = tid >> 6, lane = tid & 63;
    const int lo  = lane & 15, hi = lane >> 4;
    const int xr  = (lo & 7) << 4;         // read-side swizzle XOR (row bits)

    // --- staging geometry (linear LDS dest = chunk base + lane*16B) ---
    // K chunk c (1KB): rows 4c..4c+3, lane -> row 4c+(lane>>4), col byte (lane&15)*16
    const int krow_l  = lane >> 4;                       // 0..3
    const int kcol_sw = (((lane & 15) << 4));            // 0..240
    // V chunk c (1KB): rows 8c..8c+7, lane -> row 8c+(lane>>3), col byte (lane&7)*16
    const int vrow_l  = lane >> 3;                       // 0..7
    const int vcol_sw = ((((lane & 7) ^ (lane >> 3)) << 3)); // pre-swizzled elem off

    const size_t kbase = (size_t)bh * TT * DD;
    const size_t vbase = (size_t)bh * DD * TT;

    // Q fragments in registers: rows w*16 + lo, all of D
    const __bf16* Qbase = Q + (kbase + (size_t)(q0 + w*16 + lo) * DD);
    bf16x8 qf[4];
    #pragma unroll
    for (int kc = 0; kc < 4; ++kc)
        qf[kc] = *(const bf16x8*)(Qbase + kc*32 + hi*8);

    float mrow[4], lrow[4];
    #pragma unroll
    for (int r = 0; r < 4; ++r) { mrow[r] = -1e30f; lrow[r] = 0.f; }
    f32x4 oacc[8] = {};   // out rows q=4*hi+r, cols d = dc*16+lo

    const int qg_base = q0 + w*16 + hi*4;  // + r
    const int ntiles  = q0/64 + 1;         // causal: kv tiles 0..q0/64

    // ---- stage one tile (K + Vt) into buffer `buf`, pre-swizzled source ----
    auto stage = [&](int buf, int kv0) {
        #pragma unroll
        for (int i = 0; i < 4; ++i) {
            const int c = 4*w + i;
            {   // K: row = 4c + krow_l; src col byte = kcol_sw ^ ((row&7)<<4)
                const int row = 4*c + krow_l;
                const int sw  = (kcol_sw ^ ((row & 7) << 4)) >> 1;
                g2lds16(K + kbase + (size_t)(kv0 + row)*DD + sw,
                        &Ks[buf][0] + c*512);
            }
            {   // Vt: row(d) = 8c + vrow_l; src col elem = vcol_sw (row&7 == vrow_l)
                const int row = 8*c + vrow_l;
                g2lds16(Vt + vbase + (size_t)row*TT + kv0 + vcol_sw,
                        &Vs[buf][0] + c*512);
            }
        }
    };

    stage(0, 0);
    __syncthreads();
    int cur = 0;

    for (int t = 0; t < ntiles; ++t) {
        const int kv0 = t*64;
        if (t + 1 < ntiles) stage(cur ^ 1, (t+1)*64);

        const char* Kb = (const char*)&Ks[cur][0];
        const char* Vb = (const char*)&Vs[cur][0];

        // S = Q K^T : lane holds S[q=4hi+r][kv=st*16+lo]
        f32x4 s[4];
        #pragma unroll
        for (int st = 0; st < 4; ++st) {
            f32x4 a = {};
            #pragma unroll
            for (int kc = 0; kc < 4; ++kc) {
                const bf16x8 kf = *(const bf16x8*)(
                    Kb + (st*16 + lo)*256 + ((kc*64 + hi*16) ^ xr));
                a = MFMA16(qf[kc], kf, a);
            }
            s[st] = a;
        }

        // scale + (diagonal-only) causal mask + row max
        float pmax[4];
        const bool diag = (t == ntiles - 1);
        #pragma unroll
        for (int r = 0; r < 4; ++r) {
            const int qg = qg_base + r;
            float mx = -1e30f;
            #pragma unroll
            for (int st = 0; st < 4; ++st) {
                float v = s[st][r] * 0.08838834764831845f;
                if (diag) {
                    const int kvg = kv0 + st*16 + lo;
                    v = (kvg > qg) ? -1e30f : v;
                }
                s[st][r] = v;
                mx = fmaxf(mx, v);
            }
            #pragma unroll
            for (int msk = 1; msk < 16; msk <<= 1)
                mx = fmaxf(mx, __shfl_xor(mx, msk, 64));
            pmax[r] = mx;
        }

        float rsc[4], psum[4];
        #pragma unroll
        for (int r = 0; r < 4; ++r) {
            const float mnew = fmaxf(mrow[r], pmax[r]);
            rsc[r]  = __expf(mrow[r] - mnew);
            mrow[r] = mnew;
            float ps = 0.f;
            #pragma unroll
            for (int st = 0; st < 4; ++st) {
                const float pv = __expf(s[st][r] - mnew);
                s[st][r] = pv;
                ps += pv;
            }
            psum[r] = ps;
        }
        #pragma unroll
        for (int r = 0; r < 4; ++r) {
            #pragma unroll
            for (int msk = 1; msk < 16; msk <<= 1)
                psum[r] += __shfl_xor(psum[r], msk, 64);
            lrow[r] = lrow[r]*rsc[r] + psum[r];
        }
        #pragma unroll
        for (int dc = 0; dc < 8; ++dc)
            #pragma unroll
            for (int r = 0; r < 4; ++r)
                oacc[dc][r] *= rsc[r];

        // P -> per-wave swizzled LDS (wave-private: no barrier)
        char* Pw = (char*)&Ps[w][0];
        #pragma unroll
        for (int st = 0; st < 4; ++st)
            #pragma unroll
            for (int r = 0; r < 4; ++r) {
                const int row = hi*4 + r;
                *(__bf16*)(Pw + row*128 + (((st*16 + lo)*2) ^ ((row & 7) << 4)))
                    = (__bf16)s[st][r];
            }

        // PV: out[q][d] += P[q][kv] V[kv][d]
        #pragma unroll
        for (int kc2 = 0; kc2 < 2; ++kc2) {
            const bf16x8 pf = *(const bf16x8*)(
                Pw + lo*128 + ((kc2*64 + hi*16) ^ xr));
            #pragma unroll
            for (int dc = 0; dc < 8; ++dc) {
                const bf16x8 vf = *(const bf16x8*)(
                    Vb + (dc*16 + lo)*128 + ((kc2*64 + hi*16) ^ xr));
                oacc[dc] = MFMA16(pf, vf, oacc[dc]);
            }
        }

        __syncthreads();   // drains prefetch vmcnt + protects buffer swap
        cur ^= 1;
    }

    // epilogue: normalize and write [B,T,H*D] bf16
    const int b = bh >> 4, h = bh & 15;
    #pragma unroll
    for (int r = 0; r < 4; ++r) {
        const float inv = 1.f / lrow[r];
        const int qg = qg_base + r;
        #pragma unroll
        for (int dc = 0; dc < 8; ++dc) {
            const int d = dc*16 + lo;
            O[(size_t)(b*TT + qg)*CC + h*DD + d] = (__bf16)(oacc[dc][r] * inv);
        }
    }
}

// ---------------------------------------------------------------- launch
extern "C" void kernel_launch(void* const* d_in, const int* in_sizes, int n_in,
                              void* d_out, int out_size, void* d_ws, size_t ws_size,
                              hipStream_t stream) {
    const float* x  = (const float*)d_in[0];
    // d_in[1] = mask (causal, implemented analytically)
    const float* wq = (const float*)d_in[2];
    const float* wk = (const float*)d_in[3];
    const float* wv = (const float*)d_in[4];
    const float* wo = (const float*)d_in[5];

    char* p = (char*)d_ws;
    __bf16* xb  = (__bf16*)p; p += (size_t)MM*CC*2;   // also reused as attn-out
    __bf16* wqb = (__bf16*)p; p += (size_t)CC*CC*2;
    __bf16* wkb = (__bf16*)p; p += (size_t)CC*CC*2;
    __bf16* wvb = (__bf16*)p; p += (size_t)CC*CC*2;
    __bf16* wob = (__bf16*)p; p += (size_t)CC*CC*2;
    __bf16* Qb  = (__bf16*)p; p += (size_t)MM*CC*2;
    __bf16* Kb  = (__bf16*)p; p += (size_t)MM*CC*2;
    __bf16* Vtb = (__bf16*)p; p += (size_t)MM*CC*2;
    __bf16* AOb = xb;  // x no longer needed after QKV GEMMs (stream-ordered)

    cvt_f32_bf16<<<MM*CC/4/256, 256, 0, stream>>>(x,  xb,  MM*CC/4);
    cvt_f32_bf16<<<CC*CC/4/256, 256, 0, stream>>>(wq, wqb, CC*CC/4);
    cvt_f32_bf16<<<CC*CC/4/256, 256, 0, stream>>>(wk, wkb, CC*CC/4);
    cvt_f32_bf16<<<CC*CC/4/256, 256, 0, stream>>>(wv, wvb, CC*CC/4);
    cvt_f32_bf16<<<CC*CC/4/256, 256, 0, stream>>>(wo, wob, CC*CC/4);

    const dim3 gg(CC/128, MM/128);   // (16, 32)
    gemm_bt<0><<<gg, 256, 0, stream>>>(xb, wqb, Qb);
    gemm_bt<0><<<gg, 256, 0, stream>>>(xb, wkb, Kb);
    gemm_bt<1><<<gg, 256, 0, stream>>>(xb, wvb, Vtb);

    attn_fwd<<<dim3(TT/64, BB*HH), 256, 0, stream>>>(Qb, Kb, Vtb, AOb);

    gemm_bt<2><<<gg, 256, 0, stream>>>(AOb, wob, (void*)d_out);
}

// Round 4
// 296.684 us; speedup vs baseline: 1.5970x; 1.2267x over previous
//
#include <hip/hip_runtime.h>
#include <hip/hip_bf16.h>

// Causal attention block: out = softmax(mask(QK^T/sqrt(D))) V projections.
// B=2, T=2048, C=2048, H=16, D=128. fp32 I/O, bf16 MFMA compute internally.
//
// Pipeline:
//   1. cvt: x (f32->bf16), cvt4: wq,wk,wv,wo in one launch
//   2. gemm_bt<0>: Q = x@wq.T  -> [B,H,T,D] bf16
//      gemm_bt<0>: K = x@wk.T  -> [B,H,T,D] bf16
//      gemm_bt<1>: V = x@wv.T  -> [B,H,D,T] bf16 (transposed for PV frags)
//   3. attn_fwd: flash attention, XOR-swizzled LDS, 2-phase double buffer,
//                causal-paired blocks (uniform 33 KV-tiles/block), setprio
//   4. gemm_bt<2>: out = attn@wo.T -> fp32 d_out

#define BB 2
#define TT 2048
#define CC 2048
#define HH 16
#define DD 128
#define MM (BB*TT)   // 4096
#define NQT (TT/64)  // 32 q-tiles

typedef __bf16 bf16x8 __attribute__((ext_vector_type(8)));
typedef __bf16 bf16x4 __attribute__((ext_vector_type(4)));
typedef float  f32x4  __attribute__((ext_vector_type(4)));

#define MFMA16(a, b, c) __builtin_amdgcn_mfma_f32_16x16x32_bf16((a), (b), (c), 0, 0, 0)

__device__ __forceinline__ void g2lds16(const void* g, void* l) {
    __builtin_amdgcn_global_load_lds(
        (const __attribute__((address_space(1))) void*)g,
        (__attribute__((address_space(3))) void*)l,
        16, 0, 0);
}

// ---------------------------------------------------------------- convert
__global__ __launch_bounds__(256) void cvt_f32_bf16(
    const float* __restrict__ in, __bf16* __restrict__ out, int n4)
{
    const int i = blockIdx.x * 256 + threadIdx.x;
    if (i < n4) {
        const float4 v = ((const float4*)in)[i];
        bf16x4 o;
        o.x = (__bf16)v.x; o.y = (__bf16)v.y;
        o.z = (__bf16)v.z; o.w = (__bf16)v.w;
        ((bf16x4*)out)[i] = o;
    }
}

// 4 weight matrices (CC*CC each) in one launch; blockIdx.y selects.
__global__ __launch_bounds__(256) void cvt4_f32_bf16(
    const float* __restrict__ w0, const float* __restrict__ w1,
    const float* __restrict__ w2, const float* __restrict__ w3,
    __bf16* __restrict__ o0, __bf16* __restrict__ o1,
    __bf16* __restrict__ o2, __bf16* __restrict__ o3)
{
    const float* in; __bf16* out;
    switch (blockIdx.y) {
        case 0:  in = w0; out = o0; break;
        case 1:  in = w1; out = o1; break;
        case 2:  in = w2; out = o2; break;
        default: in = w3; out = o3; break;
    }
    const int i = blockIdx.x * 256 + threadIdx.x;
    const float4 v = ((const float4*)in)[i];
    bf16x4 o;
    o.x = (__bf16)v.x; o.y = (__bf16)v.y;
    o.z = (__bf16)v.z; o.w = (__bf16)v.w;
    ((bf16x4*)out)[i] = o;
}

// ---------------------------------------------------------------- GEMM (B^T)
// C[m][n] = sum_k A[m][k] * Wt[n][k].  M=4096, N=2048, K=2048.
// 128x128 tile, BK=32, 4 waves in 2x2, each wave 64x64 (4x4 16x16 frags).
template<int MODE>
__global__ __launch_bounds__(256, 2) void gemm_bt(
    const __bf16* __restrict__ A, const __bf16* __restrict__ Wt,
    void* __restrict__ out)
{
    __shared__ __align__(16) __bf16 As[128*32];
    __shared__ __align__(16) __bf16 Bs[128*32];

    const int n0  = blockIdx.x * 128;
    const int m0  = blockIdx.y * 128;
    const int tid = threadIdx.x;
    const int w   = tid >> 6, lane = tid & 63;
    const int wr  = w >> 1,  wc  = w & 1;
    const int lo  = lane & 15, hi = lane >> 4;
    const int rs  = lane >> 2;            // staging row within 16-row chunk
    const int cs  = (lane & 3) << 3;      // staging col elem (0,8,16,24)

    f32x4 acc[4][4] = {};

    for (int kt = 0; kt < CC/32; ++kt) {
        const int k0 = kt << 5;
        __syncthreads();
        #pragma unroll
        for (int i = 0; i < 2; ++i) {
            const int c = 2*w + i;        // 8 chunks of 1KB each for A and B
            g2lds16(A  + (size_t)(m0 + c*16 + rs)*CC + k0 + cs, As + c*512);
            g2lds16(Wt + (size_t)(n0 + c*16 + rs)*CC + k0 + cs, Bs + c*512);
        }
        __syncthreads();

        bf16x8 af[4], bfr[4];
        #pragma unroll
        for (int i = 0; i < 4; ++i) {
            af[i]  = *(const bf16x8*)(As + (wr*64 + i*16 + lo)*32 + hi*8);
            bfr[i] = *(const bf16x8*)(Bs + (wc*64 + i*16 + lo)*32 + hi*8);
        }
        #pragma unroll
        for (int i = 0; i < 4; ++i)
            #pragma unroll
            for (int j = 0; j < 4; ++j)
                acc[i][j] = MFMA16(af[i], bfr[j], acc[i][j]);
    }

    // epilogue: C/D layout col=lane&15, row=(lane>>4)*4+r  [m89-verified]
    #pragma unroll
    for (int i = 0; i < 4; ++i) {
        #pragma unroll
        for (int j = 0; j < 4; ++j) {
            #pragma unroll
            for (int r = 0; r < 4; ++r) {
                const int row = m0 + wr*64 + i*16 + hi*4 + r;   // m
                const int col = n0 + wc*64 + j*16 + lo;         // n
                const float v = acc[i][j][r];
                if (MODE == 0) {
                    const int b = row >> 11, t = row & (TT-1);
                    const int h = col >> 7,  d = col & (DD-1);
                    ((__bf16*)out)[(size_t)((b*HH + h)*TT + t)*DD + d] = (__bf16)v;
                } else if (MODE == 1) {
                    const int b = row >> 11, t = row & (TT-1);
                    const int h = col >> 7,  d = col & (DD-1);
                    ((__bf16*)out)[(size_t)((b*HH + h)*DD + d)*TT + t] = (__bf16)v;
                } else {
                    ((float*)out)[(size_t)row*CC + col] = v;
                }
            }
        }
    }
}

// ---------------------------------------------------------------- attention
// Grid (NQT/2, B*H). Each block processes TWO q-tiles: (NQT-1-x) heavy then
// (x) light -> uniform 33 KV-tiles/block, 512 blocks = exactly 2/CU.
// 4 waves/block, each wave owns 16 Q rows of the active q-tile.
// K tile [64][128] and Vt tile [128][64] XOR-swizzled, double-buffered,
// 2-phase: stage t+1 before compute t; ONE barrier per tile.
__global__ __launch_bounds__(256, 2) void attn_fwd(
    const __bf16* __restrict__ Q, const __bf16* __restrict__ K,
    const __bf16* __restrict__ Vt, __bf16* __restrict__ O)
{
    __shared__ __align__(16) __bf16 Ks[2][64*128];   // 32 KB
    __shared__ __align__(16) __bf16 Vs[2][128*64];   // 32 KB
    __shared__ __align__(16) __bf16 Ps[4][16*64];    //  8 KB

    const int bh  = blockIdx.y;            // b*H + h
    const int tid = threadIdx.x;
    const int w   = tid >> 6, lane = tid & 63;
    const int lo  = lane & 15, hi = lane >> 4;
    const int xr  = (lo & 7) << 4;         // read-side swizzle XOR (row bits)

    // staging geometry (linear LDS dest = chunk base + lane*16B)
    const int krow_l  = lane >> 4;                        // 0..3
    const int kcol_sw = ((lane & 15) << 4);               // 0..240 (bytes)
    const int vrow_l  = lane >> 3;                        // 0..7
    const int vcol_sw = (((lane & 7) ^ (lane >> 3)) << 3); // pre-swz elem off

    const size_t kbase = (size_t)bh * TT * DD;
    const size_t vbase = (size_t)bh * DD * TT;
    const int b = bh >> 4, h = bh & 15;

    auto stage = [&](int buf, int kv0) {
        #pragma unroll
        for (int i = 0; i < 4; ++i) {
            const int c = 4*w + i;
            {   // K: row = 4c + krow_l; src col byte = kcol_sw ^ ((row&7)<<4)
                const int row = 4*c + krow_l;
                const int sw  = (kcol_sw ^ ((row & 7) << 4)) >> 1;
                g2lds16(K + kbase + (size_t)(kv0 + row)*DD + sw,
                        &Ks[buf][0] + c*512);
            }
            {   // Vt: row(d) = 8c + vrow_l
                const int row = 8*c + vrow_l;
                g2lds16(Vt + vbase + (size_t)row*TT + kv0 + vcol_sw,
                        &Vs[buf][0] + c*512);
            }
        }
    };

    #pragma unroll 1
    for (int half = 0; half < 2; ++half) {
        const int qt = half ? (int)blockIdx.x : (NQT - 1 - (int)blockIdx.x);
        const int q0 = qt * 64;

        // Q fragments in registers: rows w*16 + lo, all of D
        const __bf16* Qbase = Q + (kbase + (size_t)(q0 + w*16 + lo) * DD);
        bf16x8 qf[4];
        #pragma unroll
        for (int kc = 0; kc < 4; ++kc)
            qf[kc] = *(const bf16x8*)(Qbase + kc*32 + hi*8);

        float mrow[4], lrow[4];
        #pragma unroll
        for (int r = 0; r < 4; ++r) { mrow[r] = -1e30f; lrow[r] = 0.f; }
        f32x4 oacc[8] = {};   // out rows q=4*hi+r, cols d = dc*16+lo

        const int qg_base = q0 + w*16 + hi*4;  // + r
        const int ntiles  = qt + 1;            // causal: kv tiles 0..qt

        stage(0, 0);
        __syncthreads();
        int cur = 0;

        for (int t = 0; t < ntiles; ++t) {
            const int kv0 = t*64;
            if (t + 1 < ntiles) stage(cur ^ 1, (t+1)*64);

            const char* Kb = (const char*)&Ks[cur][0];
            const char* Vb = (const char*)&Vs[cur][0];

            // S = Q K^T : lane holds S[q=4hi+r][kv=st*16+lo]
            f32x4 s[4];
            __builtin_amdgcn_s_setprio(1);
            #pragma unroll
            for (int st = 0; st < 4; ++st) {
                f32x4 a = {};
                #pragma unroll
                for (int kc = 0; kc < 4; ++kc) {
                    const bf16x8 kf = *(const bf16x8*)(
                        Kb + (st*16 + lo)*256 + ((kc*64 + hi*16) ^ xr));
                    a = MFMA16(qf[kc], kf, a);
                }
                s[st] = a;
            }
            __builtin_amdgcn_s_setprio(0);

            // scale + (diagonal-only) causal mask + row max
            float pmax[4];
            const bool diag = (t == ntiles - 1);
            #pragma unroll
            for (int r = 0; r < 4; ++r) {
                const int qg = qg_base + r;
                float mx = -1e30f;
                #pragma unroll
                for (int st = 0; st < 4; ++st) {
                    float v = s[st][r] * 0.08838834764831845f;
                    if (diag) {
                        const int kvg = kv0 + st*16 + lo;
                        v = (kvg > qg) ? -1e30f : v;
                    }
                    s[st][r] = v;
                    mx = fmaxf(mx, v);
                }
                #pragma unroll
                for (int msk = 1; msk < 16; msk <<= 1)
                    mx = fmaxf(mx, __shfl_xor(mx, msk, 64));
                pmax[r] = mx;
            }

            float rsc[4], psum[4];
            #pragma unroll
            for (int r = 0; r < 4; ++r) {
                const float mnew = fmaxf(mrow[r], pmax[r]);
                rsc[r]  = __expf(mrow[r] - mnew);
                mrow[r] = mnew;
                float ps = 0.f;
                #pragma unroll
                for (int st = 0; st < 4; ++st) {
                    const float pv = __expf(s[st][r] - mnew);
                    s[st][r] = pv;
                    ps += pv;
                }
                psum[r] = ps;
            }
            #pragma unroll
            for (int r = 0; r < 4; ++r) {
                #pragma unroll
                for (int msk = 1; msk < 16; msk <<= 1)
                    psum[r] += __shfl_xor(psum[r], msk, 64);
                lrow[r] = lrow[r]*rsc[r] + psum[r];
            }
            #pragma unroll
            for (int dc = 0; dc < 8; ++dc)
                #pragma unroll
                for (int r = 0; r < 4; ++r)
                    oacc[dc][r] *= rsc[r];

            // P -> per-wave swizzled LDS (wave-private: no barrier)
            char* Pw = (char*)&Ps[w][0];
            #pragma unroll
            for (int st = 0; st < 4; ++st)
                #pragma unroll
                for (int r = 0; r < 4; ++r) {
                    const int row = hi*4 + r;
                    *(__bf16*)(Pw + row*128 + (((st*16 + lo)*2) ^ ((row & 7) << 4)))
                        = (__bf16)s[st][r];
                }

            // PV: out[q][d] += P[q][kv] V[kv][d]
            __builtin_amdgcn_s_setprio(1);
            #pragma unroll
            for (int kc2 = 0; kc2 < 2; ++kc2) {
                const bf16x8 pf = *(const bf16x8*)(
                    Pw + lo*128 + ((kc2*64 + hi*16) ^ xr));
                #pragma unroll
                for (int dc = 0; dc < 8; ++dc) {
                    const bf16x8 vf = *(const bf16x8*)(
                        Vb + (dc*16 + lo)*128 + ((kc2*64 + hi*16) ^ xr));
                    oacc[dc] = MFMA16(pf, vf, oacc[dc]);
                }
            }
            __builtin_amdgcn_s_setprio(0);

            __syncthreads();   // drains prefetch vmcnt + protects buffer swap
            cur ^= 1;
        }

        // epilogue: normalize and write [B,T,H*D] bf16
        #pragma unroll
        for (int r = 0; r < 4; ++r) {
            const float inv = 1.f / lrow[r];
            const int qg = qg_base + r;
            #pragma unroll
            for (int dc = 0; dc < 8; ++dc) {
                const int d = dc*16 + lo;
                O[(size_t)(b*TT + qg)*CC + h*DD + d] = (__bf16)(oacc[dc][r] * inv);
            }
        }
    }
}

// ---------------------------------------------------------------- launch
extern "C" void kernel_launch(void* const* d_in, const int* in_sizes, int n_in,
                              void* d_out, int out_size, void* d_ws, size_t ws_size,
                              hipStream_t stream) {
    const float* x  = (const float*)d_in[0];
    // d_in[1] = mask (causal, implemented analytically)
    const float* wq = (const float*)d_in[2];
    const float* wk = (const float*)d_in[3];
    const float* wv = (const float*)d_in[4];
    const float* wo = (const float*)d_in[5];

    char* p = (char*)d_ws;
    __bf16* xb  = (__bf16*)p; p += (size_t)MM*CC*2;   // also reused as attn-out
    __bf16* wqb = (__bf16*)p; p += (size_t)CC*CC*2;
    __bf16* wkb = (__bf16*)p; p += (size_t)CC*CC*2;
    __bf16* wvb = (__bf16*)p; p += (size_t)CC*CC*2;
    __bf16* wob = (__bf16*)p; p += (size_t)CC*CC*2;
    __bf16* Qb  = (__bf16*)p; p += (size_t)MM*CC*2;
    __bf16* Kb  = (__bf16*)p; p += (size_t)MM*CC*2;
    __bf16* Vtb = (__bf16*)p; p += (size_t)MM*CC*2;
    __bf16* AOb = xb;  // x no longer needed after QKV GEMMs (stream-ordered)

    cvt_f32_bf16<<<MM*CC/4/256, 256, 0, stream>>>(x, xb, MM*CC/4);
    cvt4_f32_bf16<<<dim3(CC*CC/4/256, 4), 256, 0, stream>>>(
        wq, wk, wv, wo, wqb, wkb, wvb, wob);

    const dim3 gg(CC/128, MM/128);   // (16, 32)
    gemm_bt<0><<<gg, 256, 0, stream>>>(xb, wqb, Qb);
    gemm_bt<0><<<gg, 256, 0, stream>>>(xb, wkb, Kb);
    gemm_bt<1><<<gg, 256, 0, stream>>>(xb, wvb, Vtb);

    attn_fwd<<<dim3(NQT/2, BB*HH), 256, 0, stream>>>(Qb, Kb, Vtb, AOb);

    gemm_bt<2><<<gg, 256, 0, stream>>>(AOb, wob, (void*)d_out);
}